// Round 1
// baseline (324.525 us; speedup 1.0000x reference)
//
#include <hip/hip_runtime.h>
#include <hip/hip_bf16.h>

// ---- types ----
typedef __attribute__((ext_vector_type(8))) short v8s;   // 8 x bf16 (MFMA A/B frag)
typedef __attribute__((ext_vector_type(4))) short v4s;   // 4 x bf16
typedef __attribute__((ext_vector_type(4))) float v4f;   // MFMA C/D frag

#define S_LEN 2048
#define NB 4
#define NH 16

__device__ __forceinline__ short f2bf(float f) {
    __hip_bfloat16 h = __float2bfloat16(f);
    union { __hip_bfloat16 h; short s; } u; u.h = h; return u.s;
}

__device__ __forceinline__ void async16(void* lds, const void* g) {
    __builtin_amdgcn_global_load_lds(
        (const __attribute__((address_space(1))) unsigned int*)g,
        (__attribute__((address_space(3))) unsigned int*)lds, 16, 0, 0);
}

#define MFMA16(a, b, c) __builtin_amdgcn_mfma_f32_16x16x32_bf16((a), (b), (c), 0, 0, 0)

// ---------------- convert fp32 -> bf16 (vectorized, G13) ----------------
__global__ __launch_bounds__(256) void convert_f32_bf16(const float* __restrict__ in,
                                                        short* __restrict__ out) {
    size_t i = ((size_t)blockIdx.x * 256 + threadIdx.x) * 8;
    float4 a = *(const float4*)(in + i);
    float4 b = *(const float4*)(in + i + 4);
    v8s o;
    o[0] = f2bf(a.x); o[1] = f2bf(a.y); o[2] = f2bf(a.z); o[3] = f2bf(a.w);
    o[4] = f2bf(b.x); o[5] = f2bf(b.y); o[6] = f2bf(b.z); o[7] = f2bf(b.w);
    *(v8s*)(out + i) = o;
}

// ---------------- W[K][N] fp32 -> WT[N][K] bf16 ----------------
__global__ __launch_bounds__(256) void transpose_w(const float* __restrict__ W,
                                                   short* __restrict__ WT) {
    __shared__ float tile[32][33];
    int k0 = blockIdx.x * 32, n0 = blockIdx.y * 32;
    int tx = threadIdx.x & 31, ty = threadIdx.x >> 5;  // ty 0..7
#pragma unroll
    for (int i = 0; i < 4; ++i)
        tile[ty + i * 8][tx] = W[(size_t)(k0 + ty + i * 8) * 1024 + n0 + tx];
    __syncthreads();
#pragma unroll
    for (int i = 0; i < 4; ++i)
        WT[(size_t)(n0 + ty + i * 8) * 1024 + k0 + tx] = f2bf(tile[tx][ty + i * 8]);
}

// ---------------- fused QKV projection GEMM (m97 structure) ----------------
// C[8192x1024] = X[8192x1024] @ W + b ; z selects Q/K/V. 128x128 tile, BK=64.
// Q: *0.125 folded, -> [b,h,s,d]. K: -> [b,h,s,d]. V: -> transposed [b,h,d,s].
__global__ __launch_bounds__(256)
void proj_gemm(const short* __restrict__ Xq, const short* __restrict__ Xk,
               const short* __restrict__ Xv,
               const short* __restrict__ WTq, const short* __restrict__ WTk,
               const short* __restrict__ WTv,
               const float* __restrict__ bq, const float* __restrict__ bk,
               const float* __restrict__ bv,
               short* __restrict__ QW, short* __restrict__ KW, short* __restrict__ VT) {
    __shared__ short As[128 * 64];
    __shared__ short Bs[128 * 64];
    const int tid = threadIdx.x;
    const int l = tid & 63, w = tid >> 6;
    const int g = l >> 4, ql = l & 15;
    const int m0 = blockIdx.x * 128, n0 = blockIdx.y * 128;
    const int z = blockIdx.z;
    const short* A  = (z == 0) ? Xq : (z == 1) ? Xk : Xv;
    const short* BT = (z == 0) ? WTq : (z == 1) ? WTk : WTv;
    const float* bias = (z == 0) ? bq : (z == 1) ? bk : bv;
    const int wr = w >> 1, wc = w & 1;

    v4f acc[4][4] = {};

    for (int kt = 0; kt < 16; ++kt) {
        const int kk = kt * 64;
        __syncthreads();
#pragma unroll
        for (int i = 0; i < 4; ++i) {
            int ci = i * 256 + tid;
            int row = ci >> 3, c = ci & 7;
            async16((char*)As + (size_t)(i * 256 + w * 64) * 16,
                    A + (size_t)(m0 + row) * 1024 + kk + c * 8);
            async16((char*)Bs + (size_t)(i * 256 + w * 64) * 16,
                    BT + (size_t)(n0 + row) * 1024 + kk + c * 8);
        }
        __syncthreads();
#pragma unroll
        for (int ks = 0; ks < 2; ++ks) {
            v8s af[4], bfr[4];
#pragma unroll
            for (int mt = 0; mt < 4; ++mt)
                af[mt] = *(const v8s*)(As + (wr * 64 + mt * 16 + ql) * 64 + ks * 32 + g * 8);
#pragma unroll
            for (int nt = 0; nt < 4; ++nt)
                bfr[nt] = *(const v8s*)(Bs + (wc * 64 + nt * 16 + ql) * 64 + ks * 32 + g * 8);
#pragma unroll
            for (int mt = 0; mt < 4; ++mt)
#pragma unroll
                for (int nt = 0; nt < 4; ++nt)
                    acc[mt][nt] = MFMA16(af[mt], bfr[nt], acc[mt][nt]);
        }
    }

#pragma unroll
    for (int nt = 0; nt < 4; ++nt) {
        int col = n0 + wc * 64 + nt * 16 + ql;
        float bval = bias[col];
        int hh = col >> 6, dd = col & 63;
#pragma unroll
        for (int mt = 0; mt < 4; ++mt) {
#pragma unroll
            for (int r = 0; r < 4; ++r) {
                int gm = m0 + wr * 64 + mt * 16 + g * 4 + r;
                int bb = gm >> 11, ss = gm & 2047;
                float vv = acc[mt][nt][r] + bval;
                if (z == 0) {
                    vv *= 0.125f;  // 1/sqrt(64) folded into Q
                    QW[((size_t)(bb * NH + hh) * S_LEN + ss) * 64 + dd] = f2bf(vv);
                } else if (z == 1) {
                    KW[((size_t)(bb * NH + hh) * S_LEN + ss) * 64 + dd] = f2bf(vv);
                } else {
                    VT[((size_t)(bb * NH + hh) * 64 + dd) * S_LEN + ss] = f2bf(vv);
                }
            }
        }
    }
}

// ---------------- flash attention (swapped QK^T, causal + v_mask) ----------------
// grid (32 q-tiles, 64 b*h). 4 waves x 16 q-rows each. KVBLK=64.
__global__ __launch_bounds__(256)
void attn_kernel(const short* __restrict__ QW, const short* __restrict__ KW,
                 const short* __restrict__ VT, const int* __restrict__ v_mask,
                 short* __restrict__ O) {
    __shared__ short Ks[64 * 64];   // [kp][d], XOR-swizzled
    __shared__ short Vs[64 * 64];   // [d][kp], XOR-swizzled
    __shared__ short Ps[4 * 16 * 64]; // per-wave P [q][kp], swizzled
    __shared__ float vmf[64];
    __shared__ int rflag;

    const int tid = threadIdx.x;
    const int l = tid & 63, w = tid >> 6;
    const int g = l >> 4, ql = l & 15;
    const int qt = blockIdx.x, bh = blockIdx.y;
    const int b = bh >> 4, h = bh & 15;
    const int q0 = qt * 64;

    const short* Qp = QW + (size_t)bh * S_LEN * 64;
    const short* Kp = KW + (size_t)bh * S_LEN * 64;
    const short* Vp = VT + (size_t)bh * 64 * S_LEN;
    const int* vm = v_mask + b * S_LEN;

    // Q fragment (B-operand of swapped QK^T): this lane serves q-row q0+w*16+ql
    v8s qf[2];
#pragma unroll
    for (int ks = 0; ks < 2; ++ks)
        qf[ks] = *(const v8s*)(Qp + (size_t)(q0 + w * 16 + ql) * 64 + ks * 32 + g * 8);

    v4f accO[4] = {};
    float m_run = -INFINITY, l_run = 0.f;
    const int q_glob = q0 + w * 16 + ql;
    short* Pw = Ps + w * (16 * 64);

    auto process_tile = [&](int kt) {
        const int k0 = kt * 64;
        __syncthreads();
        // stage K,V (reg-staged, XOR-swizzled: rows are 128B -> 16-way conflict otherwise)
#pragma unroll
        for (int i = 0; i < 2; ++i) {
            int ci = i * 256 + tid;
            int row = ci >> 3, c = ci & 7;
            v8s kv = *(const v8s*)(Kp + (size_t)(k0 + row) * 64 + c * 8);
            *(v8s*)((char*)Ks + ((row * 128 + c * 16) ^ ((row & 7) << 4))) = kv;
            v8s vv = *(const v8s*)(Vp + (size_t)row * S_LEN + k0 + c * 8);
            *(v8s*)((char*)Vs + ((row * 128 + c * 16) ^ ((row & 7) << 4))) = vv;
        }
        if (tid < 64) vmf[tid] = (float)vm[k0 + tid];
        __syncthreads();

        // S^T = K * Q^T : acc row = kp (mt*16 + g*4 + r), col = q (ql)
        v4f s4[4] = {};
#pragma unroll
        for (int ks = 0; ks < 2; ++ks) {
#pragma unroll
            for (int mt = 0; mt < 4; ++mt) {
                int row = mt * 16 + ql;
                v8s ak = *(const v8s*)((char*)Ks +
                          ((row * 128 + ks * 64 + g * 16) ^ ((row & 7) << 4)));
                s4[mt] = MFMA16(ak, qf[ks], s4[mt]);
            }
        }
        // masks + online softmax: lane owns one q-row, holds 16 kp values
        float tmax = -INFINITY;
#pragma unroll
        for (int mt = 0; mt < 4; ++mt)
#pragma unroll
            for (int r = 0; r < 4; ++r) {
                int kpl = mt * 16 + g * 4 + r;
                float s = s4[mt][r];
                s -= (1.0f - vmf[kpl]) * 1e12f;           // v_mask penalty
                if (k0 + kpl > q_glob) s -= 1e12f;        // causal (auto-noop when kt<qt)
                s4[mt][r] = s;
                tmax = fmaxf(tmax, s);
            }
        tmax = fmaxf(tmax, __shfl_xor(tmax, 16, 64));
        tmax = fmaxf(tmax, __shfl_xor(tmax, 32, 64));
        float mnew = fmaxf(m_run, tmax);
        float scale = __expf(m_run - mnew);
        float psum = 0.f;
#pragma unroll
        for (int mt = 0; mt < 4; ++mt)
#pragma unroll
            for (int r = 0; r < 4; ++r) {
                float p = __expf(s4[mt][r] - mnew);
                s4[mt][r] = p;
                psum += p;
            }
        psum += __shfl_xor(psum, 16, 64);
        psum += __shfl_xor(psum, 32, 64);
        l_run = l_run * scale + psum;
        m_run = mnew;
        // rescale accO (rows q' = g*4+r; scale lives in lane q')
#pragma unroll
        for (int r = 0; r < 4; ++r) {
            float sc = __shfl(scale, g * 4 + r, 64);
#pragma unroll
            for (int nt = 0; nt < 4; ++nt) accO[nt][r] *= sc;
        }
        // P -> per-wave LDS [q][kp] (4 contiguous kp per reg quad -> ds_write_b64)
#pragma unroll
        for (int mt = 0; mt < 4; ++mt) {
            v4s pk;
#pragma unroll
            for (int r = 0; r < 4; ++r) pk[r] = f2bf(s4[mt][r]);
            *(v4s*)((char*)Pw + ((ql * 128 + mt * 32 + g * 8) ^ ((ql & 7) << 4))) = pk;
        }
        // PV: A = P[q][kp], B = V[kp][d] via Vs=[d][kp]
#pragma unroll
        for (int ks = 0; ks < 2; ++ks) {
            v8s ap = *(const v8s*)((char*)Pw +
                      ((ql * 128 + ks * 64 + g * 16) ^ ((ql & 7) << 4)));
#pragma unroll
            for (int nt = 0; nt < 4; ++nt) {
                int rowd = nt * 16 + ql;
                v8s bv = *(const v8s*)((char*)Vs +
                          ((rowd * 128 + ks * 64 + g * 16) ^ ((rowd & 7) << 4)));
                accO[nt] = MFMA16(ap, bv, accO[nt]);
            }
        }
    };

    for (int kt = 0; kt <= qt; ++kt) process_tile(kt);

    // Rescue pass: rows still fully masked (m_run == -1e12) must tie with
    // FUTURE keys whose score is exactly -1e12 in fp32 (reference semantics).
    for (int kt = qt + 1; kt < 32; ++kt) {
        if (tid == 0) rflag = 0;
        __syncthreads();
        if (__any(m_run < -1e11f) && l == 0) rflag = 1;
        __syncthreads();
        if (!rflag) break;
        process_tile(kt);
    }

    // epilogue: O rows q' = g*4+r, cols d = nt*16+ql
#pragma unroll
    for (int r = 0; r < 4; ++r) {
        float inv = 1.0f / __shfl(l_run, g * 4 + r, 64);
        int s_row = q0 + w * 16 + g * 4 + r;
#pragma unroll
        for (int nt = 0; nt < 4; ++nt) {
            float v = accO[nt][r] * inv;
            O[(size_t)(b * S_LEN + s_row) * 1024 + h * 64 + nt * 16 + ql] = f2bf(v);
        }
    }
}

// ---------------- output projection + bias + q_mask ----------------
__global__ __launch_bounds__(256)
void out_gemm(const short* __restrict__ A, const short* __restrict__ BT,
              const float* __restrict__ bias, const int* __restrict__ qmask,
              float* __restrict__ out) {
    __shared__ short As[128 * 64];
    __shared__ short Bs[128 * 64];
    const int tid = threadIdx.x;
    const int l = tid & 63, w = tid >> 6;
    const int g = l >> 4, ql = l & 15;
    const int m0 = blockIdx.x * 128, n0 = blockIdx.y * 128;
    const int wr = w >> 1, wc = w & 1;

    v4f acc[4][4] = {};

    for (int kt = 0; kt < 16; ++kt) {
        const int kk = kt * 64;
        __syncthreads();
#pragma unroll
        for (int i = 0; i < 4; ++i) {
            int ci = i * 256 + tid;
            int row = ci >> 3, c = ci & 7;
            async16((char*)As + (size_t)(i * 256 + w * 64) * 16,
                    A + (size_t)(m0 + row) * 1024 + kk + c * 8);
            async16((char*)Bs + (size_t)(i * 256 + w * 64) * 16,
                    BT + (size_t)(n0 + row) * 1024 + kk + c * 8);
        }
        __syncthreads();
#pragma unroll
        for (int ks = 0; ks < 2; ++ks) {
            v8s af[4], bfr[4];
#pragma unroll
            for (int mt = 0; mt < 4; ++mt)
                af[mt] = *(const v8s*)(As + (wr * 64 + mt * 16 + ql) * 64 + ks * 32 + g * 8);
#pragma unroll
            for (int nt = 0; nt < 4; ++nt)
                bfr[nt] = *(const v8s*)(Bs + (wc * 64 + nt * 16 + ql) * 64 + ks * 32 + g * 8);
#pragma unroll
            for (int mt = 0; mt < 4; ++mt)
#pragma unroll
                for (int nt = 0; nt < 4; ++nt)
                    acc[mt][nt] = MFMA16(af[mt], bfr[nt], acc[mt][nt]);
        }
    }

#pragma unroll
    for (int nt = 0; nt < 4; ++nt) {
        int col = n0 + wc * 64 + nt * 16 + ql;
        float bval = bias[col];
#pragma unroll
        for (int mt = 0; mt < 4; ++mt) {
#pragma unroll
            for (int r = 0; r < 4; ++r) {
                int gm = m0 + wr * 64 + mt * 16 + g * 4 + r;
                float vv = acc[mt][nt][r] + bval;
                vv *= (float)qmask[gm];
                out[(size_t)gm * 1024 + col] = vv;
            }
        }
    }
}

extern "C" void kernel_launch(void* const* d_in, const int* in_sizes, int n_in,
                              void* d_out, int out_size, void* d_ws, size_t ws_size,
                              hipStream_t stream) {
    (void)in_sizes; (void)n_in; (void)out_size; (void)ws_size;
    const float* q  = (const float*)d_in[0];
    const float* k  = (const float*)d_in[1];
    const float* v  = (const float*)d_in[2];
    const int* qmask = (const int*)d_in[3];
    const int* vmask = (const int*)d_in[4];
    const float* Wq = (const float*)d_in[5];
    const float* bq = (const float*)d_in[6];
    const float* Wk = (const float*)d_in[7];
    const float* bk = (const float*)d_in[8];
    const float* Wv = (const float*)d_in[9];
    const float* bv = (const float*)d_in[10];
    const float* Wo = (const float*)d_in[11];
    const float* bo = (const float*)d_in[12];
    float* out = (float*)d_out;

    char* ws = (char*)d_ws;
    const size_t MB = 1024 * 1024;
    short* Xq  = (short*)(ws + 0 * MB);
    short* Xk  = (short*)(ws + 16 * MB);
    short* Xv  = (short*)(ws + 32 * MB);
    short* WTq = (short*)(ws + 48 * MB);
    short* WTk = (short*)(ws + 50 * MB);
    short* WTv = (short*)(ws + 52 * MB);
    short* WTo = (short*)(ws + 54 * MB);
    short* QW  = (short*)(ws + 56 * MB);
    short* KW  = (short*)(ws + 72 * MB);
    short* VTb = (short*)(ws + 88 * MB);
    short* Ob  = (short*)(ws + 104 * MB);

    convert_f32_bf16<<<4096, 256, 0, stream>>>(q, Xq);
    convert_f32_bf16<<<4096, 256, 0, stream>>>(k, Xk);
    convert_f32_bf16<<<4096, 256, 0, stream>>>(v, Xv);
    transpose_w<<<dim3(32, 32), 256, 0, stream>>>(Wq, WTq);
    transpose_w<<<dim3(32, 32), 256, 0, stream>>>(Wk, WTk);
    transpose_w<<<dim3(32, 32), 256, 0, stream>>>(Wv, WTv);
    transpose_w<<<dim3(32, 32), 256, 0, stream>>>(Wo, WTo);

    proj_gemm<<<dim3(64, 8, 3), 256, 0, stream>>>(Xq, Xk, Xv, WTq, WTk, WTv,
                                                  bq, bk, bv, QW, KW, VTb);
    attn_kernel<<<dim3(32, 64), 256, 0, stream>>>(QW, KW, VTb, vmask, Ob);
    out_gemm<<<dim3(64, 8), 256, 0, stream>>>(Ob, WTo, bo, qmask, out);
}